// Round 6
// baseline (6161.128 us; speedup 1.0000x reference)
//
#include <hip/hip_runtime.h>
#include <math.h>

#define HH 256
#define FIN 6
#define TT 4096
#define BB 32
#define TH 0.05f

typedef _Float16 h2 __attribute__((ext_vector_type(2)));
struct H8 { h2 a, b, c, d; };   // 16 B = 8 halfs

__device__ __forceinline__ float hswish(float v) {
    float c = fminf(fmaxf(v + 3.0f, 0.0f), 6.0f);
    return v * c * (1.0f / 6.0f);
}
__device__ __forceinline__ float fexp2(float x) { return __builtin_amdgcn_exp2f(x); }
__device__ __forceinline__ float frcp(float x)  { return __builtin_amdgcn_rcpf(x); }
__device__ __forceinline__ float sigm(float x)  { return frcp(1.0f + fexp2(-1.44269504f * x)); }
__device__ __forceinline__ float tanhf_fast(float x) {
    float ax = fabsf(x);
    float e = fexp2(2.88539008f * ax);           // exp(2|x|)
    float t = 1.0f - 2.0f * frcp(e + 1.0f);      // tanh(|x|)
    return copysignf(t, x);
}

// Sum within each row of 16 lanes via DPP row_shr adds (VALU pipe). row_shr
// moves data toward HIGHER lanes -> sum lands in lane 15 of each 16-lane row.
__device__ __forceinline__ float dpp_row_sum16(float p) {
    int x = __float_as_int(p);
    p += __int_as_float(__builtin_amdgcn_update_dpp(0, x, 0x118, 0xF, 0xF, true)); // row_shr:8
    x = __float_as_int(p);
    p += __int_as_float(__builtin_amdgcn_update_dpp(0, x, 0x114, 0xF, 0xF, true)); // row_shr:4
    x = __float_as_int(p);
    p += __int_as_float(__builtin_amdgcn_update_dpp(0, x, 0x112, 0xF, 0xF, true)); // row_shr:2
    x = __float_as_int(p);
    p += __int_as_float(__builtin_amdgcn_update_dpp(0, x, 0x111, 0xF, 0xF, true)); // row_shr:1
    return p;  // valid in lane 15 of each 16-lane row
}

// Kernel 1: feats (B,T,6) into ws, conv skip path into d_out.
__global__ __launch_bounds__(256) void k_prep(
        const float* __restrict__ x, const float* __restrict__ Wc1,
        const float* __restrict__ Wc2, float* __restrict__ feats,
        float* __restrict__ out) {
    int idx = blockIdx.x * 256 + threadIdx.x;   // b*T + t
    if (idx >= BB * TT) return;
    int b = idx >> 12;
    int t = idx & (TT - 1);
    const float* xb = x + (size_t)b * TT * 2;
    float i0 = xb[t * 2 + 0], q0 = xb[t * 2 + 1];
    float ip = (t > 0) ? xb[(t - 1) * 2 + 0] : 0.0f;
    float qp = (t > 0) ? xb[(t - 1) * 2 + 1] : 0.0f;
    float amp2 = i0 * i0 + q0 * q0;
    float amp  = sqrtf(fmaxf(amp2, 1e-12f));
    float amp3 = amp * amp2;
    float* f = feats + (size_t)idx * 6;
    f[0] = i0; f[1] = q0; f[2] = amp; f[3] = amp3; f[4] = ip; f[5] = qp;

    float c1[3];
#pragma unroll
    for (int m = 0; m < 3; m++) {
        float acc = 0.0f;
#pragma unroll
        for (int k = 0; k < 3; k++) {
            int tt = t + (k - 1) * 16;
            if (tt >= 0 && tt < TT) {
                acc += Wc1[m * 6 + 0 * 3 + k] * xb[tt * 2 + 0];
                acc += Wc1[m * 6 + 1 * 3 + k] * xb[tt * 2 + 1];
            }
        }
        c1[m] = hswish(acc);
    }
#pragma unroll
    for (int o = 0; o < 2; o++) {
        float acc = Wc2[o * 3 + 0] * c1[0] + Wc2[o * 3 + 1] * c1[1] + Wc2[o * 3 + 2] * c1[2];
        out[(size_t)idx * 2 + o] = hswish(acc);
    }
}

// Kernel 2: delta-GRU, one block (1 CU) per batch, 1024 threads (16 waves,
// 4 per SIMD). Thread (wv, lane): row = wv*16 + (lane&15), K-quarter
// q = lane>>4 (64 of 256 K). Per-thread weights: 3 gates x 32 h2 = 96 VGPR
// -> fits the hard 128-VGPR cap of a 16-wave block (no spill), and 4
// waves/SIMD hide the write->barrier->read->dot->shuffle latency chain that
// stalled the 8-wave version (round-4/5 A/B: VALU-issue-bound, latency
// under-hidden at 2 waves/SIMD).
// mac_x is split across q too (lane handles input features 2q, 2q+1; q==3
// contributes zero) and folded into the same butterfly as the Wh dot; the
// n-gate's x-part (dmn) and h-part (dmnh) stay separate via a 4th butterfly
// value.
__global__ __launch_bounds__(1024) void k_gru(
        const float* __restrict__ feats, const float* __restrict__ Wx,
        const float* __restrict__ Wh, const float* __restrict__ Wo,
        float* __restrict__ out) {
    __shared__ float s_out[TT * 2];                    // 32 KB output accumulator
    __shared__ __align__(16) _Float16 s_dhh[2][HH];    // 1 KB, double-buffered dh (fp16)
    __shared__ __align__(16) float s_dx[2][8];         // dx (fp32), slots 6,7 = zero pad
    __shared__ float s_feat[2][128 * FIN];             // 6 KB, double-buffered feat windows

    const int tid  = threadIdx.x;
    const int wv   = tid >> 6;           // wave 0..15
    const int lane = tid & 63;
    const int q    = lane >> 4;          // K-quarter 0..3
    const int row  = wv * 16 + (lane & 15);   // 0..255
    const int b    = blockIdx.x;
    const float* fb = feats + (size_t)b * TT * FIN;

    for (int i = tid; i < TT * 2; i += 1024) s_out[i] = 0.0f;
    for (int i = tid; i < 128 * FIN; i += 1024) s_feat[0][i] = fb[i];
    if (tid < 4) s_dx[tid >> 1][6 + (tid & 1)] = 0.0f;   // q==3 pad (never written again)

    // persistent weights: 3 gate-rows, this thread's K-quarter, packed fp16.
    // wr[j] = Wh[row][q*64 + 2j, 2j+1].
    h2 wr[32], wz[32], wn[32];
    {
        const int k0 = q * 64;
        const float4* p0 = (const float4*)(Wh + (size_t)(0 * HH + row) * HH + k0);
        const float4* p1 = (const float4*)(Wh + (size_t)(1 * HH + row) * HH + k0);
        const float4* p2 = (const float4*)(Wh + (size_t)(2 * HH + row) * HH + k0);
#pragma unroll
        for (int c = 0; c < 16; c++) {
            float4 v0 = p0[c], v1 = p1[c], v2 = p2[c];
            wr[2 * c]     = h2{(_Float16)v0.x, (_Float16)v0.y};
            wr[2 * c + 1] = h2{(_Float16)v0.z, (_Float16)v0.w};
            wz[2 * c]     = h2{(_Float16)v1.x, (_Float16)v1.y};
            wz[2 * c + 1] = h2{(_Float16)v1.z, (_Float16)v1.w};
            wn[2 * c]     = h2{(_Float16)v2.x, (_Float16)v2.y};
            wn[2 * c + 1] = h2{(_Float16)v2.z, (_Float16)v2.w};
        }
    }
    // Wx slice: this lane covers input features (2q, 2q+1), fp32 exact; q==3 -> 0.
    float wxr0 = 0.0f, wxr1 = 0.0f, wxz0 = 0.0f, wxz1 = 0.0f, wxn0 = 0.0f, wxn1 = 0.0f;
    if (q < 3) {
        wxr0 = Wx[(size_t)(0 * HH + row) * FIN + 2 * q];
        wxr1 = Wx[(size_t)(0 * HH + row) * FIN + 2 * q + 1];
        wxz0 = Wx[(size_t)(1 * HH + row) * FIN + 2 * q];
        wxz1 = Wx[(size_t)(1 * HH + row) * FIN + 2 * q + 1];
        wxn0 = Wx[(size_t)(2 * HH + row) * FIN + 2 * q];
        wxn1 = Wx[(size_t)(2 * HH + row) * FIN + 2 * q + 1];
    }
    const float woc = (q < 2) ? Wo[q * HH + row] : 0.0f;  // q0 -> ch0, q1 -> ch1

    float h = 0.0f, hp = 0.0f, dmr = 0.0f, dmz = 0.0f, dmn = 0.0f, dmnh = 0.0f;
    float xp = 0.0f, curf = 0.0f;
    if (tid < FIN) curf = fb[tid];

    __syncthreads();

    for (int t = 0; t < TT; t++) {
        const int tb = t & 1;

        // stage NEXT feats window mid-way through the current one (WAR-safe)
        if ((t & 127) == 64 && t + 64 < TT) {
            const int w = (t >> 7) + 1;
            for (int i = tid; i < 128 * FIN; i += 1024)
                s_feat[w & 1][i] = fb[(size_t)w * 128 * FIN + i];
        }

        // ---- phase A: thresholded deltas (redundant in all 4 q-lanes) ----
        {
            float dh = h - hp;
            bool keep = fabsf(dh) >= TH;
            if (q == 0) s_dhh[tb][row] = (_Float16)(keep ? dh : 0.0f);
            if (keep) hp = h;
        }
        if (tid < FIN) {
            float dx = curf - xp;
            bool keep = fabsf(dx) >= TH;
            s_dx[tb][tid] = keep ? dx : 0.0f;
            if (keep) xp = curf;
        }
        __syncthreads();

        // ---- partials: 2-feature mac_x slice + quarter-K fp16 dot ----
        float ar, az, an, axn;
        {
            const float2 dxp = *((const float2*)s_dx[tb] + q);   // q==3 reads zero pad
            ar  = fmaf(dxp.x, wxr0, dxp.y * wxr1);
            az  = fmaf(dxp.x, wxz0, dxp.y * wxz1);
            axn = fmaf(dxp.x, wxn0, dxp.y * wxn1);
            an  = 0.0f;
        }
        {
            const H8* dp = (const H8*)s_dhh[tb] + q * 8;
#pragma unroll
            for (int c = 0; c < 8; c++) {
                H8 d = dp[c];
                ar = __builtin_amdgcn_fdot2(d.a, wr[4 * c + 0], ar, false);
                az = __builtin_amdgcn_fdot2(d.a, wz[4 * c + 0], az, false);
                an = __builtin_amdgcn_fdot2(d.a, wn[4 * c + 0], an, false);
                ar = __builtin_amdgcn_fdot2(d.b, wr[4 * c + 1], ar, false);
                az = __builtin_amdgcn_fdot2(d.b, wz[4 * c + 1], az, false);
                an = __builtin_amdgcn_fdot2(d.b, wn[4 * c + 1], an, false);
                ar = __builtin_amdgcn_fdot2(d.c, wr[4 * c + 2], ar, false);
                az = __builtin_amdgcn_fdot2(d.c, wz[4 * c + 2], az, false);
                an = __builtin_amdgcn_fdot2(d.c, wn[4 * c + 2], an, false);
                ar = __builtin_amdgcn_fdot2(d.d, wr[4 * c + 3], ar, false);
                az = __builtin_amdgcn_fdot2(d.d, wz[4 * c + 3], az, false);
                an = __builtin_amdgcn_fdot2(d.d, wn[4 * c + 3], an, false);
            }
        }
        // butterfly over the 4 K-quarters (lanes l, l^16, l^32, l^48)
        ar  += __shfl_xor(ar, 16, 64);  ar  += __shfl_xor(ar, 32, 64);
        az  += __shfl_xor(az, 16, 64);  az  += __shfl_xor(az, 32, 64);
        an  += __shfl_xor(an, 16, 64);  an  += __shfl_xor(an, 32, 64);
        axn += __shfl_xor(axn, 16, 64); axn += __shfl_xor(axn, 32, 64);

        dmr += ar;      // = dmr_old + dx@Wx_r + dh@Wh_r
        dmz += az;
        dmn += axn;     // x-part only
        dmnh += an;     // h-part only

        // ---- phase C (thread-local, redundant in all 4 q-lanes) ----
        {
            float r = sigm(dmr);
            float z = sigm(dmz);
            float nn = tanhf_fast(dmn + r * dmnh);
            h = (1.0f - z) * nn + z * h;
        }

        // ---- output: q-group == 16-lane DPP row; q0 -> ch0, q1 -> ch1 ----
        {
            float p = h * woc;
            p = dpp_row_sum16(p);
            if ((lane & 15) == 15 && q < 2) atomicAdd(&s_out[2 * t + q], p);
        }

        // prefetch next step's feature from LDS window
        if (tid < FIN && t + 1 < TT) {
            const int tn = t + 1;
            curf = s_feat[(tn >> 7) & 1][(tn & 127) * FIN + tid];
        }
    }

    __syncthreads();
    const size_t outbase = (size_t)b * TT * 2;
    for (int i = tid; i < TT * 2; i += 1024) out[outbase + i] += s_out[i];
}

extern "C" void kernel_launch(void* const* d_in, const int* in_sizes, int n_in,
                              void* d_out, int out_size, void* d_ws, size_t ws_size,
                              hipStream_t stream) {
    const float* x   = (const float*)d_in[0];
    const float* Wx  = (const float*)d_in[1];
    const float* Wh  = (const float*)d_in[2];
    const float* Wo  = (const float*)d_in[3];
    const float* Wc1 = (const float*)d_in[4];
    const float* Wc2 = (const float*)d_in[5];
    float* out = (float*)d_out;
    float* feats = (float*)d_ws;              // B*T*6 fp32 = 3.1 MB

    k_prep<<<(BB * TT + 255) / 256, 256, 0, stream>>>(x, Wc1, Wc2, feats, out);
    k_gru<<<BB, 1024, 0, stream>>>(feats, Wx, Wh, Wo, out);
}

// Round 8
// 5995.357 us; speedup vs baseline: 1.0276x; 1.0276x over previous
//
#include <hip/hip_runtime.h>
#include <math.h>

#define HH 256
#define FIN 6
#define TT 4096
#define BB 32
#define TH 0.05f

typedef _Float16 h2 __attribute__((ext_vector_type(2)));
struct H8 { h2 a, b, c, d; };   // 16 B = 8 halfs

__device__ __forceinline__ float hswish(float v) {
    float c = fminf(fmaxf(v + 3.0f, 0.0f), 6.0f);
    return v * c * (1.0f / 6.0f);
}
__device__ __forceinline__ float fexp2(float x) { return __builtin_amdgcn_exp2f(x); }
__device__ __forceinline__ float frcp(float x)  { return __builtin_amdgcn_rcpf(x); }
__device__ __forceinline__ float sigm(float x)  { return frcp(1.0f + fexp2(-1.44269504f * x)); }
__device__ __forceinline__ float tanhf_fast(float x) {
    float ax = fabsf(x);
    float e = fexp2(2.88539008f * ax);           // exp(2|x|)
    float t = 1.0f - 2.0f * frcp(e + 1.0f);      // tanh(|x|)
    return copysignf(t, x);
}

// Sum within each row of 16 lanes via DPP row_shr adds (VALU pipe). row_shr
// moves data toward HIGHER lanes -> sum lands in lane 15 of each 16-lane row.
__device__ __forceinline__ float dpp_row_sum16(float p) {
    int x = __float_as_int(p);
    p += __int_as_float(__builtin_amdgcn_update_dpp(0, x, 0x118, 0xF, 0xF, true)); // row_shr:8
    x = __float_as_int(p);
    p += __int_as_float(__builtin_amdgcn_update_dpp(0, x, 0x114, 0xF, 0xF, true)); // row_shr:4
    x = __float_as_int(p);
    p += __int_as_float(__builtin_amdgcn_update_dpp(0, x, 0x112, 0xF, 0xF, true)); // row_shr:2
    x = __float_as_int(p);
    p += __int_as_float(__builtin_amdgcn_update_dpp(0, x, 0x111, 0xF, 0xF, true)); // row_shr:1
    return p;  // valid in lane 15 of each 16-lane row
}

// Kernel 1: feats (B,T,6) into ws, conv skip path into d_out.
__global__ __launch_bounds__(256) void k_prep(
        const float* __restrict__ x, const float* __restrict__ Wc1,
        const float* __restrict__ Wc2, float* __restrict__ feats,
        float* __restrict__ out) {
    int idx = blockIdx.x * 256 + threadIdx.x;   // b*T + t
    if (idx >= BB * TT) return;
    int b = idx >> 12;
    int t = idx & (TT - 1);
    const float* xb = x + (size_t)b * TT * 2;
    float i0 = xb[t * 2 + 0], q0 = xb[t * 2 + 1];
    float ip = (t > 0) ? xb[(t - 1) * 2 + 0] : 0.0f;
    float qp = (t > 0) ? xb[(t - 1) * 2 + 1] : 0.0f;
    float amp2 = i0 * i0 + q0 * q0;
    float amp  = sqrtf(fmaxf(amp2, 1e-12f));
    float amp3 = amp * amp2;
    float* f = feats + (size_t)idx * 6;
    f[0] = i0; f[1] = q0; f[2] = amp; f[3] = amp3; f[4] = ip; f[5] = qp;

    float c1[3];
#pragma unroll
    for (int m = 0; m < 3; m++) {
        float acc = 0.0f;
#pragma unroll
        for (int k = 0; k < 3; k++) {
            int tt = t + (k - 1) * 16;
            if (tt >= 0 && tt < TT) {
                acc += Wc1[m * 6 + 0 * 3 + k] * xb[tt * 2 + 0];
                acc += Wc1[m * 6 + 1 * 3 + k] * xb[tt * 2 + 1];
            }
        }
        c1[m] = hswish(acc);
    }
#pragma unroll
    for (int o = 0; o < 2; o++) {
        float acc = Wc2[o * 3 + 0] * c1[0] + Wc2[o * 3 + 1] * c1[1] + Wc2[o * 3 + 2] * c1[2];
        out[(size_t)idx * 2 + o] = hswish(acc);
    }
}

// --- named-scalar weight storage: zero aggregate semantics, SROA-proof ---
// NOTE: macro param must NOT be named `c`/`a`/`b`/`d` -- the body accesses
// struct members .a/.b/.c/.d and the preprocessor substitutes into member
// access (round-7 compile failure: DOTC(0) -> d_.0).
#define DECLC(g, CC) h2 g##_##CC##_0, g##_##CC##_1, g##_##CC##_2, g##_##CC##_3;
#define LOADC(g, p, CC) { float4 va_ = (p)[2 * (CC)], vb_ = (p)[2 * (CC) + 1]; \
    g##_##CC##_0 = h2{(_Float16)va_.x, (_Float16)va_.y};                       \
    g##_##CC##_1 = h2{(_Float16)va_.z, (_Float16)va_.w};                       \
    g##_##CC##_2 = h2{(_Float16)vb_.x, (_Float16)vb_.y};                       \
    g##_##CC##_3 = h2{(_Float16)vb_.z, (_Float16)vb_.w}; }
#define DOTC(CC) { H8 dd_ = dp[CC];                                            \
    ar = __builtin_amdgcn_fdot2(dd_.a, wr_##CC##_0, ar, false);                \
    az = __builtin_amdgcn_fdot2(dd_.a, wz_##CC##_0, az, false);                \
    an = __builtin_amdgcn_fdot2(dd_.a, wn_##CC##_0, an, false);                \
    ar = __builtin_amdgcn_fdot2(dd_.b, wr_##CC##_1, ar, false);                \
    az = __builtin_amdgcn_fdot2(dd_.b, wz_##CC##_1, az, false);                \
    an = __builtin_amdgcn_fdot2(dd_.b, wn_##CC##_1, an, false);                \
    ar = __builtin_amdgcn_fdot2(dd_.c, wr_##CC##_2, ar, false);                \
    az = __builtin_amdgcn_fdot2(dd_.c, wz_##CC##_2, az, false);                \
    an = __builtin_amdgcn_fdot2(dd_.c, wn_##CC##_2, an, false);                \
    ar = __builtin_amdgcn_fdot2(dd_.d, wr_##CC##_3, ar, false);                \
    az = __builtin_amdgcn_fdot2(dd_.d, wz_##CC##_3, az, false);                \
    an = __builtin_amdgcn_fdot2(dd_.d, wn_##CC##_3, an, false); }

// Kernel 2: delta-GRU, one block (1 CU) per batch, 1024 threads (16 waves,
// 4/SIMD). Thread (wv, lane): row = wv*16 + (lane&15), K-quarter q = lane>>4.
// Per-thread weights: 3 gates x 32 h2 = 96 regs, stored as NAMED SCALARS.
//
// Diagnosis from rounds 0-6: the allocator sizes the register budget for
// 2 blocks/CU (budget = 65536/block_threads: 512->128, 1024->64 observed),
// so the weight state was ALWAYS in scratch (WRITE_SIZE ~11-12.5 MB =
// one-time spill write-back; per-step L2 scratch reloads = the invariant
// ~3000 cyc/step). Fix requires BOTH: waves_per_eu(4,4) pins the budget to
// 512/4 = 128 for the single resident 16-wave block, and named scalars
// guarantee promotion. Need ~120 <= 128.
__global__ __launch_bounds__(1024)
__attribute__((amdgpu_waves_per_eu(4, 4))) void k_gru(
        const float* __restrict__ feats, const float* __restrict__ Wx,
        const float* __restrict__ Wh, const float* __restrict__ Wo,
        float* __restrict__ out) {
    __shared__ float s_out[TT * 2];                    // 32 KB output accumulator
    __shared__ __align__(16) _Float16 s_dhh[2][HH];    // 1 KB, double-buffered dh (fp16)
    __shared__ __align__(16) float s_dx[2][8];         // dx (fp32), slots 6,7 = zero pad
    __shared__ float s_feat[2][128 * FIN];             // 6 KB, double-buffered feat windows

    const int tid  = threadIdx.x;
    const int wv   = tid >> 6;           // wave 0..15
    const int lane = tid & 63;
    const int q    = lane >> 4;          // K-quarter 0..3
    const int row  = wv * 16 + (lane & 15);   // 0..255
    const int b    = blockIdx.x;
    const float* fb = feats + (size_t)b * TT * FIN;

    for (int i = tid; i < TT * 2; i += 1024) s_out[i] = 0.0f;
    for (int i = tid; i < 128 * FIN; i += 1024) s_feat[0][i] = fb[i];
    if (tid < 4) s_dx[tid >> 1][6 + (tid & 1)] = 0.0f;   // q==3 pad (never written again)

    // persistent weights: 3 gate-rows, this thread's K-quarter.
    // (g)_c_j = Wh[gate g, row][q*64 + 8c + 2j .. +1] as packed fp16.
    DECLC(wr, 0) DECLC(wr, 1) DECLC(wr, 2) DECLC(wr, 3)
    DECLC(wr, 4) DECLC(wr, 5) DECLC(wr, 6) DECLC(wr, 7)
    DECLC(wz, 0) DECLC(wz, 1) DECLC(wz, 2) DECLC(wz, 3)
    DECLC(wz, 4) DECLC(wz, 5) DECLC(wz, 6) DECLC(wz, 7)
    DECLC(wn, 0) DECLC(wn, 1) DECLC(wn, 2) DECLC(wn, 3)
    DECLC(wn, 4) DECLC(wn, 5) DECLC(wn, 6) DECLC(wn, 7)
    {
        const int k0 = q * 64;
        const float4* p0 = (const float4*)(Wh + (size_t)(0 * HH + row) * HH + k0);
        const float4* p1 = (const float4*)(Wh + (size_t)(1 * HH + row) * HH + k0);
        const float4* p2 = (const float4*)(Wh + (size_t)(2 * HH + row) * HH + k0);
        LOADC(wr, p0, 0) LOADC(wr, p0, 1) LOADC(wr, p0, 2) LOADC(wr, p0, 3)
        LOADC(wr, p0, 4) LOADC(wr, p0, 5) LOADC(wr, p0, 6) LOADC(wr, p0, 7)
        LOADC(wz, p1, 0) LOADC(wz, p1, 1) LOADC(wz, p1, 2) LOADC(wz, p1, 3)
        LOADC(wz, p1, 4) LOADC(wz, p1, 5) LOADC(wz, p1, 6) LOADC(wz, p1, 7)
        LOADC(wn, p2, 0) LOADC(wn, p2, 1) LOADC(wn, p2, 2) LOADC(wn, p2, 3)
        LOADC(wn, p2, 4) LOADC(wn, p2, 5) LOADC(wn, p2, 6) LOADC(wn, p2, 7)
    }
    // Wx slice: this lane covers input features (2q, 2q+1), fp32 exact; q==3 -> 0.
    float wxr0 = 0.0f, wxr1 = 0.0f, wxz0 = 0.0f, wxz1 = 0.0f, wxn0 = 0.0f, wxn1 = 0.0f;
    if (q < 3) {
        wxr0 = Wx[(size_t)(0 * HH + row) * FIN + 2 * q];
        wxr1 = Wx[(size_t)(0 * HH + row) * FIN + 2 * q + 1];
        wxz0 = Wx[(size_t)(1 * HH + row) * FIN + 2 * q];
        wxz1 = Wx[(size_t)(1 * HH + row) * FIN + 2 * q + 1];
        wxn0 = Wx[(size_t)(2 * HH + row) * FIN + 2 * q];
        wxn1 = Wx[(size_t)(2 * HH + row) * FIN + 2 * q + 1];
    }
    const float woc = (q < 2) ? Wo[q * HH + row] : 0.0f;  // q0 -> ch0, q1 -> ch1

    float h = 0.0f, hp = 0.0f, dmr = 0.0f, dmz = 0.0f, dmn = 0.0f, dmnh = 0.0f;
    float xp = 0.0f, curf = 0.0f;
    if (tid < FIN) curf = fb[tid];

    __syncthreads();

    for (int t = 0; t < TT; t++) {
        const int tb = t & 1;

        // stage NEXT feats window mid-way through the current one (WAR-safe)
        if ((t & 127) == 64 && t + 64 < TT) {
            const int w = (t >> 7) + 1;
            for (int i = tid; i < 128 * FIN; i += 1024)
                s_feat[w & 1][i] = fb[(size_t)w * 128 * FIN + i];
        }

        // ---- phase A: thresholded deltas (redundant in all 4 q-lanes) ----
        {
            float dh = h - hp;
            bool keep = fabsf(dh) >= TH;
            if (q == 0) s_dhh[tb][row] = (_Float16)(keep ? dh : 0.0f);
            if (keep) hp = h;
        }
        if (tid < FIN) {
            float dx = curf - xp;
            bool keep = fabsf(dx) >= TH;
            s_dx[tb][tid] = keep ? dx : 0.0f;
            if (keep) xp = curf;
        }
        __syncthreads();

        // ---- partials: 2-feature mac_x slice + quarter-K fp16 dot ----
        float ar, az, an, axn;
        {
            const float2 dxp = *((const float2*)s_dx[tb] + q);   // q==3 reads zero pad
            ar  = fmaf(dxp.x, wxr0, dxp.y * wxr1);
            az  = fmaf(dxp.x, wxz0, dxp.y * wxz1);
            axn = fmaf(dxp.x, wxn0, dxp.y * wxn1);
            an  = 0.0f;
        }
        {
            const H8* dp = (const H8*)s_dhh[tb] + q * 8;
            DOTC(0) DOTC(1) DOTC(2) DOTC(3)
            DOTC(4) DOTC(5) DOTC(6) DOTC(7)
        }
        // butterfly over the 4 K-quarters (lanes l, l^16, l^32, l^48)
        ar  += __shfl_xor(ar, 16, 64);  ar  += __shfl_xor(ar, 32, 64);
        az  += __shfl_xor(az, 16, 64);  az  += __shfl_xor(az, 32, 64);
        an  += __shfl_xor(an, 16, 64);  an  += __shfl_xor(an, 32, 64);
        axn += __shfl_xor(axn, 16, 64); axn += __shfl_xor(axn, 32, 64);

        dmr += ar;      // = dmr_old + dx@Wx_r + dh@Wh_r
        dmz += az;
        dmn += axn;     // x-part only
        dmnh += an;     // h-part only

        // ---- phase C (thread-local, redundant in all 4 q-lanes) ----
        {
            float r = sigm(dmr);
            float z = sigm(dmz);
            float nn = tanhf_fast(dmn + r * dmnh);
            h = (1.0f - z) * nn + z * h;
        }

        // ---- output: q-group == 16-lane DPP row; q0 -> ch0, q1 -> ch1 ----
        {
            float p = h * woc;
            p = dpp_row_sum16(p);
            if ((lane & 15) == 15 && q < 2) atomicAdd(&s_out[2 * t + q], p);
        }

        // prefetch next step's feature from LDS window
        if (tid < FIN && t + 1 < TT) {
            const int tn = t + 1;
            curf = s_feat[(tn >> 7) & 1][(tn & 127) * FIN + tid];
        }
    }

    __syncthreads();
    const size_t outbase = (size_t)b * TT * 2;
    for (int i = tid; i < TT * 2; i += 1024) out[outbase + i] += s_out[i];
}

extern "C" void kernel_launch(void* const* d_in, const int* in_sizes, int n_in,
                              void* d_out, int out_size, void* d_ws, size_t ws_size,
                              hipStream_t stream) {
    const float* x   = (const float*)d_in[0];
    const float* Wx  = (const float*)d_in[1];
    const float* Wh  = (const float*)d_in[2];
    const float* Wo  = (const float*)d_in[3];
    const float* Wc1 = (const float*)d_in[4];
    const float* Wc2 = (const float*)d_in[5];
    float* out = (float*)d_out;
    float* feats = (float*)d_ws;              // B*T*6 fp32 = 3.1 MB

    k_prep<<<(BB * TT + 255) / 256, 256, 0, stream>>>(x, Wc1, Wc2, feats, out);
    k_gru<<<BB, 1024, 0, stream>>>(feats, Wx, Wh, Wo, out);
}

// Round 10
// 5169.252 us; speedup vs baseline: 1.1919x; 1.1598x over previous
//
#include <hip/hip_runtime.h>
#include <math.h>

#define HH 256
#define FIN 6
#define TT 4096
#define BB 32
#define TH 0.05f

typedef _Float16 h2 __attribute__((ext_vector_type(2)));
struct __align__(16) H8 { h2 a, b, c, d; };   // 16 B = 8 halfs

__device__ __forceinline__ float hswish(float v) {
    float c = fminf(fmaxf(v + 3.0f, 0.0f), 6.0f);
    return v * c * (1.0f / 6.0f);
}
__device__ __forceinline__ float fexp2(float x) { return __builtin_amdgcn_exp2f(x); }
__device__ __forceinline__ float frcp(float x)  { return __builtin_amdgcn_rcpf(x); }
__device__ __forceinline__ float sigm(float x)  { return frcp(1.0f + fexp2(-1.44269504f * x)); }
__device__ __forceinline__ float tanhf_fast(float x) {
    float ax = fabsf(x);
    float e = fexp2(2.88539008f * ax);           // exp(2|x|)
    float t = 1.0f - 2.0f * frcp(e + 1.0f);      // tanh(|x|)
    return copysignf(t, x);
}

// DPP row_shr sum over 16 lanes (VALU pipe); sum lands in lane 15 of each row.
__device__ __forceinline__ float dpp_row_sum16(float p) {
    int x = __float_as_int(p);
    p += __int_as_float(__builtin_amdgcn_update_dpp(0, x, 0x118, 0xF, 0xF, true));
    x = __float_as_int(p);
    p += __int_as_float(__builtin_amdgcn_update_dpp(0, x, 0x114, 0xF, 0xF, true));
    x = __float_as_int(p);
    p += __int_as_float(__builtin_amdgcn_update_dpp(0, x, 0x112, 0xF, 0xF, true));
    x = __float_as_int(p);
    p += __int_as_float(__builtin_amdgcn_update_dpp(0, x, 0x111, 0xF, 0xF, true));
    return p;
}

// Kernel 1: feats (B,T,6) into ws, conv skip path into d_out.
__global__ __launch_bounds__(256) void k_prep(
        const float* __restrict__ x, const float* __restrict__ Wc1,
        const float* __restrict__ Wc2, float* __restrict__ feats,
        float* __restrict__ out) {
    int idx = blockIdx.x * 256 + threadIdx.x;   // b*T + t
    if (idx >= BB * TT) return;
    int b = idx >> 12;
    int t = idx & (TT - 1);
    const float* xb = x + (size_t)b * TT * 2;
    float i0 = xb[t * 2 + 0], q0 = xb[t * 2 + 1];
    float ip = (t > 0) ? xb[(t - 1) * 2 + 0] : 0.0f;
    float qp = (t > 0) ? xb[(t - 1) * 2 + 1] : 0.0f;
    float amp2 = i0 * i0 + q0 * q0;
    float amp  = sqrtf(fmaxf(amp2, 1e-12f));
    float amp3 = amp * amp2;
    float* f = feats + (size_t)idx * 6;
    f[0] = i0; f[1] = q0; f[2] = amp; f[3] = amp3; f[4] = ip; f[5] = qp;

    float c1[3];
#pragma unroll
    for (int m = 0; m < 3; m++) {
        float acc = 0.0f;
#pragma unroll
        for (int k = 0; k < 3; k++) {
            int tt = t + (k - 1) * 16;
            if (tt >= 0 && tt < TT) {
                acc += Wc1[m * 6 + 0 * 3 + k] * xb[tt * 2 + 0];
                acc += Wc1[m * 6 + 1 * 3 + k] * xb[tt * 2 + 1];
            }
        }
        c1[m] = hswish(acc);
    }
#pragma unroll
    for (int o = 0; o < 2; o++) {
        float acc = Wc2[o * 3 + 0] * c1[0] + Wc2[o * 3 + 1] * c1[1] + Wc2[o * 3 + 2] * c1[2];
        out[(size_t)idx * 2 + o] = hswish(acc);
    }
}

// Kernel 1b: prepack z and n gate weights to fp16 in [chunk c][slice] layout.
// slice = half*256 + row; chunk c = 8 contiguous cols (16 B) at half*128+8c.
__global__ __launch_bounds__(256) void k_pack(
        const float* __restrict__ Wh, _Float16* __restrict__ zp,
        _Float16* __restrict__ np) {
    int id = blockIdx.x * 256 + threadIdx.x;     // 0..16383
    if (id >= 16384) return;
    int which = id >> 13;                         // 0 = z(gate1), 1 = n(gate2)
    int c     = (id >> 9) & 15;                   // chunk 0..15
    int slice = id & 511;
    int row = slice & 255, half = slice >> 8;
    int g = 1 + which;
    const float* src = Wh + ((size_t)(g * HH + row)) * HH + half * 128 + 8 * c;
    _Float16* dst = (which ? np : zp) + ((size_t)c * 512 + slice) * 8;
#pragma unroll
    for (int j = 0; j < 8; j++) dst[j] = (_Float16)src[j];
}

// Per-chunk dots: r from registers, z from LDS, n from the streamed reg NR.
#define CH(CC, NR) { H8 zw_ = zl[(CC) * 512]; H8 dd_ = dp[CC];                 \
    ar0 = __builtin_amdgcn_fdot2(dd_.a, wr[4 * (CC) + 0], ar0, false);         \
    az0 = __builtin_amdgcn_fdot2(dd_.a, zw_.a, az0, false);                    \
    an0 = __builtin_amdgcn_fdot2(dd_.a, NR.a, an0, false);                     \
    ar1 = __builtin_amdgcn_fdot2(dd_.b, wr[4 * (CC) + 1], ar1, false);         \
    az1 = __builtin_amdgcn_fdot2(dd_.b, zw_.b, az1, false);                    \
    an1 = __builtin_amdgcn_fdot2(dd_.b, NR.b, an1, false);                     \
    ar0 = __builtin_amdgcn_fdot2(dd_.c, wr[4 * (CC) + 2], ar0, false);         \
    az0 = __builtin_amdgcn_fdot2(dd_.c, zw_.c, az0, false);                    \
    an0 = __builtin_amdgcn_fdot2(dd_.c, NR.c, an0, false);                     \
    ar1 = __builtin_amdgcn_fdot2(dd_.d, wr[4 * (CC) + 3], ar1, false);         \
    az1 = __builtin_amdgcn_fdot2(dd_.d, zw_.d, az1, false);                    \
    an1 = __builtin_amdgcn_fdot2(dd_.d, NR.d, an1, false); }

// Kernel 2: delta-GRU, 512 threads, lanes (l,l+32) own row wv*32+(l&31),
// K-half = lane>>5. THREE-TIER weight residency (the allocator caps VGPRs
// at 65536/threads; the old full-register design spilled 384 KB/CU of Wh
// to scratch and re-streamed it from L2 every step at the ~130 B/cyc L2
// ceiling = the measured ~3000 cyc/step floor). Tiers: r-gate in registers
// (64 h2), z-gate LDS-permanent (128 KB, separate pipe), n-gate streamed
// from L2 (128 KB/step, prepacked fp16, 8-deep pipelined).
// Round-9 fix: mac_x back to fp32 (fp16 dx on |amp3|~100 features broke
// accumulated precision: absmax 0.167). fp32 mac_x is SPLIT across K-halves
// (half 0: features 0-2, half 1: 3-5; 9 fp32 Wx regs) and folded into the
// existing xor32 butterfly; 4th butterfly value keeps n's x-part separate.
__global__ __launch_bounds__(512) void k_gru(
        const float* __restrict__ feats, const float* __restrict__ Wx,
        const float* __restrict__ Wh, const float* __restrict__ Wo,
        const _Float16* __restrict__ zp, const _Float16* __restrict__ np,
        float* __restrict__ out) {
    extern __shared__ __align__(16) _Float16 z_lds[];      // 128 KB dynamic
    __shared__ __align__(16) _Float16 s_dhh[2][HH];        // 1 KB dh (fp16)
    __shared__ __align__(16) float s_dx[2][8];             // dx fp32, 6 used

    const int tid  = threadIdx.x;
    const int wv   = tid >> 6;
    const int lane = tid & 63;
    const int half = lane >> 5;
    const int row  = wv * 32 + (lane & 31);
    const int slice = half * 256 + row;
    const int b    = blockIdx.x;
    const float* fb = feats + (size_t)b * TT * FIN;
    float* outb = out + (size_t)b * TT * 2;

    // one-time: stage full z-gate (fp16, [c][slice] layout) into LDS
    for (int i = tid; i < 8192; i += 512)
        ((float4*)z_lds)[i] = ((const float4*)zp)[i];

    // resident r-gate weights: this row, this K-half (64 h2 = 64 VGPRs)
    h2 wr[64];
    {
        const float4* p0 = (const float4*)(Wh + (size_t)(0 * HH + row) * HH + half * 128);
#pragma unroll
        for (int c = 0; c < 32; c++) {
            float4 v0 = p0[c];
            wr[2 * c]     = h2{(_Float16)v0.x, (_Float16)v0.y};
            wr[2 * c + 1] = h2{(_Float16)v0.z, (_Float16)v0.w};
        }
    }
    // Wx slice (fp32 exact): this half covers features 3*half .. 3*half+2.
    float wxr0, wxr1, wxr2, wxz0, wxz1, wxz2, wxn0, wxn1, wxn2;
    {
        const int f0 = 3 * half;
        wxr0 = Wx[(size_t)(0 * HH + row) * FIN + f0];
        wxr1 = Wx[(size_t)(0 * HH + row) * FIN + f0 + 1];
        wxr2 = Wx[(size_t)(0 * HH + row) * FIN + f0 + 2];
        wxz0 = Wx[(size_t)(1 * HH + row) * FIN + f0];
        wxz1 = Wx[(size_t)(1 * HH + row) * FIN + f0 + 1];
        wxz2 = Wx[(size_t)(1 * HH + row) * FIN + f0 + 2];
        wxn0 = Wx[(size_t)(2 * HH + row) * FIN + f0];
        wxn1 = Wx[(size_t)(2 * HH + row) * FIN + f0 + 1];
        wxn2 = Wx[(size_t)(2 * HH + row) * FIN + f0 + 2];
    }
    const float woc = Wo[half * HH + row];

    float h = 0.0f, hp = 0.0f, dmr = 0.0f, dmz = 0.0f, dmn = 0.0f, dmnh = 0.0f;
    float xp = 0.0f, curf = 0.0f;
    if (tid < FIN) curf = fb[tid];

    const H8* zl = (const H8*)z_lds + slice;     // chunk c at zl[c*512]
    const H8* nl = (const H8*)np + slice;        // global, chunk c at nl[c*512]

    __syncthreads();

    for (int t = 0; t < TT; t++) {
        const int tb = t & 1;

        // ---- phase A: thresholded deltas ----
        {
            float dh = h - hp;
            bool keep = fabsf(dh) >= TH;
            if (half == 0) s_dhh[tb][row] = (_Float16)(keep ? dh : 0.0f);
            if (keep) hp = h;
        }
        if (tid < FIN) {
            float dx = curf - xp;
            bool keep = fabsf(dx) >= TH;
            s_dx[tb][tid] = keep ? dx : 0.0f;
            if (keep) xp = curf;
        }
        __syncthreads();

        // ---- mac_x slice (fp32, 3 features of this half) ----
        float dxa = s_dx[tb][3 * half], dxb = s_dx[tb][3 * half + 1],
              dxc = s_dx[tb][3 * half + 2];
        float ar0 = fmaf(dxa, wxr0, fmaf(dxb, wxr1, dxc * wxr2));
        float az0 = fmaf(dxa, wxz0, fmaf(dxb, wxz1, dxc * wxz2));
        float axn = fmaf(dxa, wxn0, fmaf(dxb, wxn1, dxc * wxn2));
        float ar1 = 0.0f, az1 = 0.0f, an0 = 0.0f, an1 = 0.0f;

        // ---- fused r/z/n dots; n streamed from L2, groups of 4, 1 ahead ----
        const H8* dp = (const H8*)s_dhh[tb] + half * 16;
        {
            H8 na0 = nl[0 * 512],  na1 = nl[1 * 512],  na2 = nl[2 * 512],  na3 = nl[3 * 512];
            H8 nb0 = nl[4 * 512],  nb1 = nl[5 * 512],  nb2 = nl[6 * 512],  nb3 = nl[7 * 512];
            CH(0, na0) CH(1, na1) CH(2, na2) CH(3, na3)
            na0 = nl[8 * 512];  na1 = nl[9 * 512];  na2 = nl[10 * 512]; na3 = nl[11 * 512];
            CH(4, nb0) CH(5, nb1) CH(6, nb2) CH(7, nb3)
            nb0 = nl[12 * 512]; nb1 = nl[13 * 512]; nb2 = nl[14 * 512]; nb3 = nl[15 * 512];
            CH(8, na0) CH(9, na1) CH(10, na2) CH(11, na3)
            CH(12, nb0) CH(13, nb1) CH(14, nb2) CH(15, nb3)
        }
        float ar = ar0 + ar1, az = az0 + az1, an = an0 + an1;
        // butterfly across K-halves: completes dh-dots AND the mac_x halves
        ar  += __shfl_xor(ar, 32, 64);
        az  += __shfl_xor(az, 32, 64);
        an  += __shfl_xor(an, 32, 64);
        axn += __shfl_xor(axn, 32, 64);

        dmr += ar;      // dmr_prev + dx@Wx_r + dh@Wh_r
        dmz += az;
        dmn += axn;     // x-part only
        dmnh += an;     // h-part only

        // ---- phase C ----
        {
            float r = sigm(dmr);
            float z = sigm(dmz);
            float nn = tanhf_fast(dmn + r * dmnh);
            h = (1.0f - z) * nn + z * h;
        }

        // ---- output: direct global atomics ----
        {
            float p = h * woc;
            p += __shfl_xor(p, 16, 64);
            p = dpp_row_sum16(p);
            if ((lane & 31) == 31) atomicAdd(&outb[2 * t + half], p);
        }

        // prefetch next step's feature straight from global (latency hidden)
        if (tid < FIN && t + 1 < TT) curf = fb[(size_t)(t + 1) * FIN + tid];
    }
}

extern "C" void kernel_launch(void* const* d_in, const int* in_sizes, int n_in,
                              void* d_out, int out_size, void* d_ws, size_t ws_size,
                              hipStream_t stream) {
    const float* x   = (const float*)d_in[0];
    const float* Wx  = (const float*)d_in[1];
    const float* Wh  = (const float*)d_in[2];
    const float* Wo  = (const float*)d_in[3];
    const float* Wc1 = (const float*)d_in[4];
    const float* Wc2 = (const float*)d_in[5];
    float* out = (float*)d_out;
    float* feats = (float*)d_ws;                                   // 3.07 MB
    _Float16* zp = (_Float16*)((char*)d_ws + 3145728);             // 128 KB
    _Float16* np = (_Float16*)((char*)d_ws + 3145728 + 131072);    // 128 KB

    k_prep<<<(BB * TT + 255) / 256, 256, 0, stream>>>(x, Wc1, Wc2, feats, out);
    k_pack<<<64, 256, 0, stream>>>(Wh, zp, np);
    hipFuncSetAttribute(reinterpret_cast<const void*>(k_gru),
                        hipFuncAttributeMaxDynamicSharedMemorySize, 131072);
    k_gru<<<BB, 512, 131072, stream>>>(feats, Wx, Wh, Wo, zp, np, out);
}